// Round 17
// baseline (166.217 us; speedup 1.0000x reference)
//
#include <hip/hip_runtime.h>
#include <hip/hip_bf16.h>

static constexpr float SLOPE = 0.01f;   // leaky_relu negative_slope
static constexpr float EPSN  = 1e-12f;  // F.normalize eps

typedef float f32x4 __attribute__((ext_vector_type(4)));
typedef short short8 __attribute__((ext_vector_type(8)));

#define KPAD 512     // in_dim = 500 padded to 16 k-steps of 32 (8 tiles of 64)

// VALU (DPP) butterfly/rotate add: x + dpp(x). No DS-pipe traffic.
// 0xB1=quad_perm xor1; 0x4E=quad_perm xor2; 0x124=row_ror:4; 0x128=row_ror:8.
template <int CTRL>
__device__ __forceinline__ float dpp_add(float x) {
  const int y = __builtin_amdgcn_mov_dpp(__builtin_bit_cast(int, x), CTRL, 0xF, 0xF, true);
  return x + __builtin_bit_cast(float, y);
}

// round-to-nearest bf16 split: v ~= hi + lo, each exactly representable in bf16
__device__ __forceinline__ void bf16_split(float v, short& hi, short& lo) {
  __hip_bfloat16 h = __float2bfloat16(v);
  float hf = __bfloat162float(h);
  __hip_bfloat16 l = __float2bfloat16(v - hf);
  hi = __builtin_bit_cast(short, h);
  lo = __builtin_bit_cast(short, l);
}

// async global->LDS DMA, 16B per lane. LDS dest = base + lane*16 (linear).
__device__ __forceinline__ void load_lds16(const float* g, float* l) {
  __builtin_amdgcn_global_load_lds(
      (const __attribute__((address_space(1))) unsigned int*)g,
      (__attribute__((address_space(3))) unsigned int*)l, 16, 0, 0);
}

// ---------------------------------------------------------------------------
// One-time W prep: split to bf16 hi/lo, swizzle to w2[kstep][kc][col][8],
// zero-pad k to KPAD. Also zeroes the 16B zbuf used for A-tail redirect.
// ---------------------------------------------------------------------------
__global__ __launch_bounds__(256) void prep_w_k(const float* __restrict__ W,
                                                short* __restrict__ w2h,
                                                short* __restrict__ w2l,
                                                float* __restrict__ zbuf, int in_dim) {
  const int idx = blockIdx.x * 256 + threadIdx.x;   // over KPAD*64
  if (idx < 4) zbuf[idx] = 0.0f;
  if (idx >= KPAD * 64) return;
  const int k = idx >> 6, col = idx & 63;
  const float v = (k < in_dim) ? W[(size_t)k * 64 + col] : 0.0f;
  short hi, lo;
  bf16_split(v, hi, lo);
  const int kt = k >> 5, kc = (k >> 3) & 3, e = k & 7;
  const int off = (((kt * 4 + kc) * 64) + col) * 8 + e;
  w2h[off] = hi;
  w2l[off] = lo;
}

// ---------------------------------------------------------------------------
// Stage one 16-row x 64-float A tile via 4 async DMA calls (r9 structure).
// ---------------------------------------------------------------------------
__device__ __forceinline__ void stage_tile(const float* __restrict__ x,
                                           const float* __restrict__ zbuf,
                                           float* ldsbuf, int row0w, int kt,
                                           int n, int in_dim, int lane) {
  const int rl = lane >> 4;          // row within 4-row call group
  const int gl = lane & 15;          // destination granule slot
#pragma unroll
  for (int i = 0; i < 4; ++i) {
    const int r    = i * 4 + rl;
    const int gsrc = gl ^ (r & 7);
    const int k    = kt * 64 + gsrc * 4;
    int grow = row0w + r;
    grow = grow < n ? grow : n - 1;
    const float* src = (k + 4 <= in_dim) ? (x + (size_t)grow * in_dim + k) : zbuf;
    load_lds16(src, ldsbuf + i * 256);   // 4 rows * 64 floats per call
  }
}

// ---------------------------------------------------------------------------
// Fused MFMA GEMM (r9/r14 structure, measured 62-64us -- the floor across 7
// structural variants; per-CU memory-request-queue bound; FROZEN):
// xn = capsnorm(leaky_relu(x @ W + b)). Per-wave-private double-buffered A
// tiles staged with global_load_lds; B from pre-swizzled w2h/w2l (L2).
// ---------------------------------------------------------------------------
__global__ __launch_bounds__(256) void gemm_mfma_capsnorm_k(
    const float* __restrict__ x, const short* __restrict__ w2h,
    const short* __restrict__ w2l, const float* __restrict__ b,
    const float* __restrict__ zbuf, float* __restrict__ xn, int n, int in_dim) {
  __shared__ __align__(16) float xs[4][2][1024];   // [wave][buf][16 rows x 64 f]

  const int tid   = threadIdx.x;
  const int lane  = tid & 63;
  const int w     = tid >> 6;
  const int l15   = lane & 15;
  const int kcL   = lane >> 4;
  const int row0  = blockIdx.x * 64;
  const int row0w = row0 + w * 16;
  const int sw4   = l15 & 7;

  f32x4 acc0 = {0.f, 0.f, 0.f, 0.f};
  f32x4 acc1 = {0.f, 0.f, 0.f, 0.f};
  f32x4 acc2 = {0.f, 0.f, 0.f, 0.f};
  f32x4 acc3 = {0.f, 0.f, 0.f, 0.f};

  stage_tile(x, zbuf, &xs[w][0][0], row0w, 0, n, in_dim, lane);

  for (int kt = 0; kt < 8; ++kt) {
    float* cur = &xs[w][kt & 1][0];
    float* nxt = &xs[w][(kt & 1) ^ 1][0];

    const int s00 = ((kcL * 2)     ^ sw4) * 4;
    const int s01 = ((kcL * 2 + 1) ^ sw4) * 4;
    const int s10 = ((8 + kcL * 2)     ^ sw4) * 4;
    const int s11 = ((8 + kcL * 2 + 1) ^ sw4) * 4;
    const float4 fa0 = *reinterpret_cast<const float4*>(&cur[l15 * 64 + s00]);
    const float4 fb0 = *reinterpret_cast<const float4*>(&cur[l15 * 64 + s01]);
    const float4 fa1 = *reinterpret_cast<const float4*>(&cur[l15 * 64 + s10]);
    const float4 fb1 = *reinterpret_cast<const float4*>(&cur[l15 * 64 + s11]);

    if (kt < 7) stage_tile(x, zbuf, nxt, row0w, kt + 1, n, in_dim, lane);

#pragma unroll
    for (int ks = 0; ks < 2; ++ks) {
      const float4 A0 = ks ? fa1 : fa0;
      const float4 A1 = ks ? fb1 : fb0;
      short hb[8], lb[8];
      bf16_split(A0.x, hb[0], lb[0]);
      bf16_split(A0.y, hb[1], lb[1]);
      bf16_split(A0.z, hb[2], lb[2]);
      bf16_split(A0.w, hb[3], lb[3]);
      bf16_split(A1.x, hb[4], lb[4]);
      bf16_split(A1.y, hb[5], lb[5]);
      bf16_split(A1.z, hb[6], lb[6]);
      bf16_split(A1.w, hb[7], lb[7]);
      const short8 ah = *reinterpret_cast<const short8*>(hb);
      const short8 al = *reinterpret_cast<const short8*>(lb);
      const int ktg = kt * 2 + ks;
      const size_t base = ((size_t)(ktg * 4 + kcL) * 64) * 8;
#pragma unroll
      for (int nt = 0; nt < 4; ++nt) {
        const short8 bh = *reinterpret_cast<const short8*>(w2h + base + (size_t)(nt * 16 + l15) * 8);
        const short8 bl = *reinterpret_cast<const short8*>(w2l + base + (size_t)(nt * 16 + l15) * 8);
        f32x4& acc = nt == 0 ? acc0 : nt == 1 ? acc1 : nt == 2 ? acc2 : acc3;
        acc = __builtin_amdgcn_mfma_f32_16x16x32_bf16(ah, bh, acc, 0, 0, 0);
        acc = __builtin_amdgcn_mfma_f32_16x16x32_bf16(ah, bl, acc, 0, 0, 0);
        acc = __builtin_amdgcn_mfma_f32_16x16x32_bf16(al, bh, acc, 0, 0, 0);
      }
    }
  }

  // --- epilogue: bias + leaky_relu + capsnorm ---
#pragma unroll
  for (int nt = 0; nt < 4; ++nt) {
    const f32x4 acc = nt == 0 ? acc0 : nt == 1 ? acc1 : nt == 2 ? acc2 : acc3;
    const float bcol = b[nt * 16 + l15];
#pragma unroll
    for (int reg = 0; reg < 4; ++reg) {
      float v = acc[reg] + bcol;
      v = v > 0.f ? v : SLOPE * v;
      float s = v * v;
      s = dpp_add<0xB1>(s);        // xor1 (VALU)
      s = dpp_add<0x4E>(s);        // xor2 (VALU)
      s += __shfl_xor(s, 4);       // xor4
      const float inv = 1.0f / fmaxf(sqrtf(s), EPSN);
      const int grow = row0 + w * 16 + ((lane >> 4) << 2) + reg;
      if (grow < n) xn[(size_t)grow * 64 + nt * 16 + l15] = v * inv;
    }
  }
}

// ---------------------------------------------------------------------------
// CSR construction (proven chain): memset -> hist -> scanA -> scanB -> scanC
// -> scatter.
// ---------------------------------------------------------------------------
__global__ __launch_bounds__(256) void hist_k(const int* __restrict__ trg,
                                              int* __restrict__ counts, int m) {
  const int e = blockIdx.x * blockDim.x + threadIdx.x;
  if (e < m) atomicAdd(&counts[trg[e]], 1);
}

__global__ __launch_bounds__(256) void scanA_k(const int* __restrict__ counts,
                                               int* __restrict__ bsum, int n) {
  const int i = blockIdx.x * 256 + threadIdx.x;
  int v = (i < n) ? counts[i] : 0;
  v += __shfl_xor(v, 1);  v += __shfl_xor(v, 2);  v += __shfl_xor(v, 4);
  v += __shfl_xor(v, 8);  v += __shfl_xor(v, 16); v += __shfl_xor(v, 32);
  __shared__ int wsum[4];
  if ((threadIdx.x & 63) == 0) wsum[threadIdx.x >> 6] = v;
  __syncthreads();
  if (threadIdx.x == 0) bsum[blockIdx.x] = wsum[0] + wsum[1] + wsum[2] + wsum[3];
}

__global__ __launch_bounds__(256) void scanB_k(int* __restrict__ bsum, int nblk,
                                               int* __restrict__ row_ptr, int n, int m) {
  const int i = threadIdx.x;
  const int lane = i & 63;
  const int wave = i >> 6;
  const int v = (i < nblk) ? bsum[i] : 0;
  int inc = v;
#pragma unroll
  for (int d = 1; d < 64; d <<= 1) {
    int t = __shfl_up(inc, d);
    if (lane >= d) inc += t;
  }
  __shared__ int wsum[4];
  if (lane == 63) wsum[wave] = inc;
  __syncthreads();
  int base = 0;
  for (int q = 0; q < wave; ++q) base += wsum[q];
  if (i < nblk) bsum[i] = base + inc - v;
  if (i == 0) row_ptr[n] = m;
}

__global__ __launch_bounds__(256) void scanC_k(const int* __restrict__ counts,
                                               const int* __restrict__ bsum,
                                               int* __restrict__ row_ptr,
                                               int* __restrict__ cursor, int n) {
  const int i = blockIdx.x * 256 + threadIdx.x;
  const int lane = threadIdx.x & 63;
  const int wave = threadIdx.x >> 6;
  const int v = (i < n) ? counts[i] : 0;
  int inc = v;
#pragma unroll
  for (int d = 1; d < 64; d <<= 1) {
    int t = __shfl_up(inc, d);
    if (lane >= d) inc += t;
  }
  __shared__ int wsum[4];
  if (lane == 63) wsum[wave] = inc;
  __syncthreads();
  int base = bsum[blockIdx.x];
  for (int q = 0; q < wave; ++q) base += wsum[q];
  const int excl = base + inc - v;
  if (i < n) { row_ptr[i] = excl; cursor[i] = excl; }
}

__global__ __launch_bounds__(256) void scatter_k(const int* __restrict__ src,
                                                 const int* __restrict__ trg,
                                                 int* __restrict__ cursor,
                                                 int* __restrict__ src_sorted, int m) {
  const int e = blockIdx.x * blockDim.x + threadIdx.x;
  if (e < m) {
    const int pos = atomicAdd(&cursor[trg[e]], 1);
    src_sorted[pos] = src[e];
  }
}

// ---------------------------------------------------------------------------
// One FULL routing layer (3 iterations fused), wave-per-node, 16 lanes/edge.
// REGISTER-RESIDENT edge cache (r13/r14) + DEGREE-EXACT quartile branching:
// deg is wave-uniform, so both the gather and the EDGE_BODY calls for edge
// quartiles [4,8), [8,12), [12,16) are guarded by uniform branches. Padded
// slots contributed exactly 0 (z=0 -> msg=0), so skipping them is identical
// math while cutting mean VALU work/node from 16 slots to ~11.6 (deg~Poisson
// 10) and skipping ~37% of gather instructions.
// MODE 1: dst = capsnorm(lrelu(u3))   (layer boundary)
// MODE 2: dst = lrelu(u3)             (final output)
// ---------------------------------------------------------------------------
template <int MODE>
__global__ __launch_bounds__(256) void rout_layer_k(
    const int* __restrict__ row_ptr, const int* __restrict__ src_sorted,
    const float* __restrict__ xn, float* __restrict__ dst, int n) {
  const int wid  = blockIdx.x * 4 + (threadIdx.x >> 6);
  const int lane = threadIdx.x & 63;
  if (wid >= n) return;
  const int g = lane >> 4;          // edge slot 0..3
  const int q = lane & 15;          // float4 chunk (dims 4q..4q+3)
  const size_t rowj = (size_t)wid * 64 + q * 4;
  const float4 fz = make_float4(0.f, 0.f, 0.f, 0.f);

  const float4 xj = *reinterpret_cast<const float4*>(xn + rowj);
  float u0 = xj.x, u1 = xj.y, u2 = xj.z, u3 = xj.w;   // u = x initially

  const int e0  = row_ptr[wid];
  const int end = row_ptr[wid + 1];
  const int deg = end - e0;                  // wave-uniform
  const int ntile = (deg + 3) >> 2;

  // ---- batched register gather of the first 16 edges (degree-exact) ----
  float4 zA = fz, zB = fz, zC = fz, zD = fz;
  if (deg > 0) {
    const int eA = e0 + g;
    const bool vA = eA < end;
    const int iA = vA ? src_sorted[eA] : wid;
    float4 t = *reinterpret_cast<const float4*>(xn + (size_t)iA * 64 + q * 4);
    if (vA) zA = t;
  }
  if (deg > 4) {
    const int eB = e0 + 4 + g;
    const bool vB = eB < end;
    const int iB = vB ? src_sorted[eB] : wid;
    float4 t = *reinterpret_cast<const float4*>(xn + (size_t)iB * 64 + q * 4);
    if (vB) zB = t;
  }
  if (deg > 8) {
    const int eC = e0 + 8 + g;
    const bool vC = eC < end;
    const int iC = vC ? src_sorted[eC] : wid;
    float4 t = *reinterpret_cast<const float4*>(xn + (size_t)iC * 64 + q * 4);
    if (vC) zC = t;
  }
  if (deg > 12) {
    const int eD = e0 + 12 + g;
    const bool vD = eD < end;
    const int iD = vD ? src_sorted[eD] : wid;
    float4 t = *reinterpret_cast<const float4*>(xn + (size_t)iD * 64 + q * 4);
    if (vD) zD = t;
  }

  for (int t = 0; t < 3; ++t) {
    float a0 = 0.f, a1 = 0.f, a2 = 0.f, a3 = 0.f;

#define EDGE_BODY(Z)                                                   \
    {                                                                  \
      float d = (Z).x * u0;                                            \
      d = fmaf((Z).y, u1, d);                                          \
      d = fmaf((Z).z, u2, d);                                          \
      d = fmaf((Z).w, u3, d);                                          \
      d = dpp_add<0xB1>(d);              /* 8-dim capsule dot */       \
      const float ee = __expf(d);        /* |d|<=1: unit capsules */   \
      float sm = dpp_add<0x4E>(ee);      /* + capsule c^1        */    \
      sm = dpp_add<0x124>(sm);           /* + ror4               */    \
      sm = dpp_add<0x128>(sm);           /* + ror8: all 8 caps   */    \
      const float wgt = ee * __builtin_amdgcn_rcpf(sm);                \
      a0 = fmaf((Z).x, wgt, a0);                                       \
      a1 = fmaf((Z).y, wgt, a1);                                       \
      a2 = fmaf((Z).z, wgt, a2);                                       \
      a3 = fmaf((Z).w, wgt, a3);                                       \
    }

    // degree-exact: skip quartiles past deg (wave-uniform branches;
    // padded slots would contribute exactly 0, so math is identical)
    if (deg > 0)  EDGE_BODY(zA)
    if (deg > 4)  EDGE_BODY(zB)
    if (deg > 8)  EDGE_BODY(zC)
    if (deg > 12) EDGE_BODY(zD)
    // overflow (deg > 16): re-gather per iteration
    for (int it = 4; it < ntile; ++it) {
      const int e = e0 + it * 4 + g;
      const bool vv = e < end;
      const int ss = vv ? src_sorted[e] : wid;
      float4 z = *reinterpret_cast<const float4*>(xn + (size_t)ss * 64 + q * 4);
      if (!vv) z = fz;
      EDGE_BODY(z)
    }
#undef EDGE_BODY

    // combine the 4 edge slots (lane bits 4,5)
    a0 += __shfl_xor(a0, 16); a0 += __shfl_xor(a0, 32);
    a1 += __shfl_xor(a1, 16); a1 += __shfl_xor(a1, 32);
    a2 += __shfl_xor(a2, 16); a2 += __shfl_xor(a2, 32);
    a3 += __shfl_xor(a3, 16); a3 += __shfl_xor(a3, 32);
    // + x, capsnorm -> next u
    a0 += xj.x; a1 += xj.y; a2 += xj.z; a3 += xj.w;
    float ss = a0 * a0 + a1 * a1 + a2 * a2 + a3 * a3;
    ss = dpp_add<0xB1>(ss);
    const float inv = 1.0f / fmaxf(sqrtf(ss), EPSN);
    u0 = a0 * inv; u1 = a1 * inv; u2 = a2 * inv; u3 = a3 * inv;
  }

  // boundary transforms
  float v0 = u0, v1 = u1, v2 = u2, v3 = u3;
  v0 = v0 > 0.f ? v0 : SLOPE * v0;
  v1 = v1 > 0.f ? v1 : SLOPE * v1;
  v2 = v2 > 0.f ? v2 : SLOPE * v2;
  v3 = v3 > 0.f ? v3 : SLOPE * v3;
  if (MODE == 1) {   // re-capsnorm for next layer's x
    float s3 = v0 * v0 + v1 * v1 + v2 * v2 + v3 * v3;
    s3 = dpp_add<0xB1>(s3);
    const float inv3 = 1.0f / fmaxf(sqrtf(s3), EPSN);
    v0 *= inv3; v1 *= inv3; v2 *= inv3; v3 *= inv3;
  }
  if (g == 0) {
    *reinterpret_cast<float4*>(dst + rowj) = make_float4(v0, v1, v2, v3);
  }
}

// ---------------------------------------------------------------------------
extern "C" void kernel_launch(void* const* d_in, const int* in_sizes, int n_in,
                              void* d_out, int out_size, void* d_ws, size_t ws_size,
                              hipStream_t stream) {
  const float* x       = (const float*)d_in[0];
  const int*   src_trg = (const int*)d_in[1];
  const float* W       = (const float*)d_in[2];
  const float* b       = (const float*)d_in[3];

  const int hid    = in_sizes[3];          // 64
  const int in_dim = in_sizes[2] / hid;    // 500
  const int n      = in_sizes[0] / in_dim; // 50000
  const int m      = in_sizes[1] / 2;      // 500000
  const int* src = src_trg;
  const int* trg = src_trg + m;

  const size_t n64 = (size_t)n * hid;      // 3.2M floats
  float* xn_a = (float*)d_ws;              // layer-1 normalized features
  float* xn_b = xn_a + n64;                // layer-2 normalized features
  short* w2h  = (short*)(xn_b + n64);      // KPAD*64 bf16 hi (swizzled)
  short* w2l  = w2h + KPAD * 64;           // KPAD*64 bf16 lo
  float* zbuf = (float*)(w2l + KPAD * 64); // 16B zero granule (A-tail redirect)
  int*   ip   = (int*)(zbuf + 4);
  int* counts     = ip;                    // n
  int* row_ptr    = counts + n;            // n+1
  int* cursor     = row_ptr + n + 1;       // n
  int* bsum       = cursor + n;            // nblk
  const int nblk  = (n + 255) / 256;       // 196 (<= 256 required by scanB)
  int* src_sorted = bsum + nblk;           // m
  float* out = (float*)d_out;

  const int mg = (m + 255) / 256;

  // --- CSR build (proven 3-kernel scan chain) ---
  hipMemsetAsync(counts, 0, (size_t)n * sizeof(int), stream);
  hist_k<<<mg, 256, 0, stream>>>(trg, counts, m);
  scanA_k<<<nblk, 256, 0, stream>>>(counts, bsum, n);
  scanB_k<<<1, 256, 0, stream>>>(bsum, nblk, row_ptr, n, m);
  scanC_k<<<nblk, 256, 0, stream>>>(counts, bsum, row_ptr, cursor, n);
  scatter_k<<<mg, 256, 0, stream>>>(src, trg, cursor, src_sorted, m);

  // --- W prep + fused MFMA GEMM: xn_a = capsnorm(lrelu(x @ W + b)) ---
  prep_w_k<<<(KPAD * 64) / 256, 256, 0, stream>>>(W, w2h, w2l, zbuf, in_dim);
  gemm_mfma_capsnorm_k<<<(n + 63) / 64, 256, 0, stream>>>(
      x, w2h, w2l, b, zbuf, xn_a, n, in_dim);

  // --- routing: one fused kernel per layer (3 iterations each) ---
  const int rb = (n + 3) / 4;  // 4 waves (nodes) per 256-thread block
  rout_layer_k<1><<<rb, 256, 0, stream>>>(row_ptr, src_sorted, xn_a, xn_b, n);
  rout_layer_k<2><<<rb, 256, 0, stream>>>(row_ptr, src_sorted, xn_b, out, n);
}

// Round 18
// 147.260 us; speedup vs baseline: 1.1287x; 1.1287x over previous
//
#include <hip/hip_runtime.h>
#include <hip/hip_bf16.h>

static constexpr float SLOPE = 0.01f;   // leaky_relu negative_slope
static constexpr float EPSN  = 1e-12f;  // F.normalize eps

typedef float f32x4 __attribute__((ext_vector_type(4)));
typedef short short8 __attribute__((ext_vector_type(8)));

#define KPAD 512     // in_dim = 500 padded to 16 k-steps of 32 (8 tiles of 64)
#define PREP_BLOCKS (KPAD * 64 / 256)   // 128

// VALU (DPP) butterfly/rotate add: x + dpp(x). No DS-pipe traffic.
// 0xB1=quad_perm xor1; 0x4E=quad_perm xor2; 0x124=row_ror:4; 0x128=row_ror:8.
template <int CTRL>
__device__ __forceinline__ float dpp_add(float x) {
  const int y = __builtin_amdgcn_mov_dpp(__builtin_bit_cast(int, x), CTRL, 0xF, 0xF, true);
  return x + __builtin_bit_cast(float, y);
}

// round-to-nearest bf16 split: v ~= hi + lo, each exactly representable in bf16
__device__ __forceinline__ void bf16_split(float v, short& hi, short& lo) {
  __hip_bfloat16 h = __float2bfloat16(v);
  float hf = __bfloat162float(h);
  __hip_bfloat16 l = __float2bfloat16(v - hf);
  hi = __builtin_bit_cast(short, h);
  lo = __builtin_bit_cast(short, l);
}

// async global->LDS DMA, 16B per lane. LDS dest = base + lane*16 (linear).
__device__ __forceinline__ void load_lds16(const float* g, float* l) {
  __builtin_amdgcn_global_load_lds(
      (const __attribute__((address_space(1))) unsigned int*)g,
      (__attribute__((address_space(3))) unsigned int*)l, 16, 0, 0);
}

// ---------------------------------------------------------------------------
// FUSED: prep_w (blocks [0,PREP_BLOCKS)) + hist (remaining blocks).
// Independent outputs (w2h/w2l/zbuf vs counts) -> legal to co-schedule.
// ---------------------------------------------------------------------------
__global__ __launch_bounds__(256) void prep_hist_k(
    const float* __restrict__ W, short* __restrict__ w2h,
    short* __restrict__ w2l, float* __restrict__ zbuf, int in_dim,
    const int* __restrict__ trg, int* __restrict__ counts, int m) {
  if ((int)blockIdx.x < PREP_BLOCKS) {
    const int idx = blockIdx.x * 256 + threadIdx.x;   // over KPAD*64
    if (idx < 4) zbuf[idx] = 0.0f;
    if (idx >= KPAD * 64) return;
    const int k = idx >> 6, col = idx & 63;
    const float v = (k < in_dim) ? W[(size_t)k * 64 + col] : 0.0f;
    short hi, lo;
    bf16_split(v, hi, lo);
    const int kt = k >> 5, kc = (k >> 3) & 3, e = k & 7;
    const int off = (((kt * 4 + kc) * 64) + col) * 8 + e;
    w2h[off] = hi;
    w2l[off] = lo;
  } else {
    const int e = (blockIdx.x - PREP_BLOCKS) * 256 + threadIdx.x;
    if (e < m) atomicAdd(&counts[trg[e]], 1);
  }
}

// ---------------------------------------------------------------------------
// Stage one 16-row x 64-float A tile via 4 async DMA calls (r9 structure).
// ---------------------------------------------------------------------------
__device__ __forceinline__ void stage_tile(const float* __restrict__ x,
                                           const float* __restrict__ zbuf,
                                           float* ldsbuf, int row0w, int kt,
                                           int n, int in_dim, int lane) {
  const int rl = lane >> 4;          // row within 4-row call group
  const int gl = lane & 15;          // destination granule slot
#pragma unroll
  for (int i = 0; i < 4; ++i) {
    const int r    = i * 4 + rl;
    const int gsrc = gl ^ (r & 7);
    const int k    = kt * 64 + gsrc * 4;
    int grow = row0w + r;
    grow = grow < n ? grow : n - 1;
    const float* src = (k + 4 <= in_dim) ? (x + (size_t)grow * in_dim + k) : zbuf;
    load_lds16(src, ldsbuf + i * 256);   // 4 rows * 64 floats per call
  }
}

// ---------------------------------------------------------------------------
// FUSED: MFMA GEMM (blocks [0,gemm_blocks)) + CSR scatter (remaining blocks).
// GEMM (r9/r14 structure, 62-64us, per-CU memory-request-queue bound) runs at
// Occ 28% / VALUBusy 13% -- its waves mostly wait on memory. Scatter's atomic
// blocks stream into those idle issue slots (disjoint buffers; GEMM body has
// no __syncthreads, so the block-uniform branch is safe).
// ---------------------------------------------------------------------------
__global__ __launch_bounds__(256) void gemm_scatter_k(
    const float* __restrict__ x, const short* __restrict__ w2h,
    const short* __restrict__ w2l, const float* __restrict__ b,
    const float* __restrict__ zbuf, float* __restrict__ xn, int n, int in_dim,
    const int* __restrict__ src, const int* __restrict__ trg,
    int* __restrict__ cursor, int* __restrict__ src_sorted, int m,
    int gemm_blocks) {
  __shared__ __align__(16) float xs[4][2][1024];   // [wave][buf][16 rows x 64 f]

  if ((int)blockIdx.x >= gemm_blocks) {
    // ---- scatter path ----
    const int e = (blockIdx.x - gemm_blocks) * 256 + threadIdx.x;
    if (e < m) {
      const int pos = atomicAdd(&cursor[trg[e]], 1);
      src_sorted[pos] = src[e];
    }
    return;
  }

  // ---- GEMM path ----
  const int tid   = threadIdx.x;
  const int lane  = tid & 63;
  const int w     = tid >> 6;
  const int l15   = lane & 15;
  const int kcL   = lane >> 4;
  const int row0  = blockIdx.x * 64;
  const int row0w = row0 + w * 16;
  const int sw4   = l15 & 7;

  f32x4 acc0 = {0.f, 0.f, 0.f, 0.f};
  f32x4 acc1 = {0.f, 0.f, 0.f, 0.f};
  f32x4 acc2 = {0.f, 0.f, 0.f, 0.f};
  f32x4 acc3 = {0.f, 0.f, 0.f, 0.f};

  stage_tile(x, zbuf, &xs[w][0][0], row0w, 0, n, in_dim, lane);

  for (int kt = 0; kt < 8; ++kt) {
    float* cur = &xs[w][kt & 1][0];
    float* nxt = &xs[w][(kt & 1) ^ 1][0];

    const int s00 = ((kcL * 2)     ^ sw4) * 4;
    const int s01 = ((kcL * 2 + 1) ^ sw4) * 4;
    const int s10 = ((8 + kcL * 2)     ^ sw4) * 4;
    const int s11 = ((8 + kcL * 2 + 1) ^ sw4) * 4;
    const float4 fa0 = *reinterpret_cast<const float4*>(&cur[l15 * 64 + s00]);
    const float4 fb0 = *reinterpret_cast<const float4*>(&cur[l15 * 64 + s01]);
    const float4 fa1 = *reinterpret_cast<const float4*>(&cur[l15 * 64 + s10]);
    const float4 fb1 = *reinterpret_cast<const float4*>(&cur[l15 * 64 + s11]);

    if (kt < 7) stage_tile(x, zbuf, nxt, row0w, kt + 1, n, in_dim, lane);

#pragma unroll
    for (int ks = 0; ks < 2; ++ks) {
      const float4 A0 = ks ? fa1 : fa0;
      const float4 A1 = ks ? fb1 : fb0;
      short hb[8], lb[8];
      bf16_split(A0.x, hb[0], lb[0]);
      bf16_split(A0.y, hb[1], lb[1]);
      bf16_split(A0.z, hb[2], lb[2]);
      bf16_split(A0.w, hb[3], lb[3]);
      bf16_split(A1.x, hb[4], lb[4]);
      bf16_split(A1.y, hb[5], lb[5]);
      bf16_split(A1.z, hb[6], lb[6]);
      bf16_split(A1.w, hb[7], lb[7]);
      const short8 ah = *reinterpret_cast<const short8*>(hb);
      const short8 al = *reinterpret_cast<const short8*>(lb);
      const int ktg = kt * 2 + ks;
      const size_t base = ((size_t)(ktg * 4 + kcL) * 64) * 8;
#pragma unroll
      for (int nt = 0; nt < 4; ++nt) {
        const short8 bh = *reinterpret_cast<const short8*>(w2h + base + (size_t)(nt * 16 + l15) * 8);
        const short8 bl = *reinterpret_cast<const short8*>(w2l + base + (size_t)(nt * 16 + l15) * 8);
        f32x4& acc = nt == 0 ? acc0 : nt == 1 ? acc1 : nt == 2 ? acc2 : acc3;
        acc = __builtin_amdgcn_mfma_f32_16x16x32_bf16(ah, bh, acc, 0, 0, 0);
        acc = __builtin_amdgcn_mfma_f32_16x16x32_bf16(ah, bl, acc, 0, 0, 0);
        acc = __builtin_amdgcn_mfma_f32_16x16x32_bf16(al, bh, acc, 0, 0, 0);
      }
    }
  }

  // --- epilogue: bias + leaky_relu + capsnorm ---
#pragma unroll
  for (int nt = 0; nt < 4; ++nt) {
    const f32x4 acc = nt == 0 ? acc0 : nt == 1 ? acc1 : nt == 2 ? acc2 : acc3;
    const float bcol = b[nt * 16 + l15];
#pragma unroll
    for (int reg = 0; reg < 4; ++reg) {
      float v = acc[reg] + bcol;
      v = v > 0.f ? v : SLOPE * v;
      float s = v * v;
      s = dpp_add<0xB1>(s);        // xor1 (VALU)
      s = dpp_add<0x4E>(s);        // xor2 (VALU)
      s += __shfl_xor(s, 4);       // xor4
      const float inv = 1.0f / fmaxf(sqrtf(s), EPSN);
      const int grow = row0 + w * 16 + ((lane >> 4) << 2) + reg;
      if (grow < n) xn[(size_t)grow * 64 + nt * 16 + l15] = v * inv;
    }
  }
}

// ---------------------------------------------------------------------------
// CSR scan chain (proven): scanA (per-block sums) -> scanB (1-block parallel
// scan) -> scanC (intra-block offsets).
// ---------------------------------------------------------------------------
__global__ __launch_bounds__(256) void scanA_k(const int* __restrict__ counts,
                                               int* __restrict__ bsum, int n) {
  const int i = blockIdx.x * 256 + threadIdx.x;
  int v = (i < n) ? counts[i] : 0;
  v += __shfl_xor(v, 1);  v += __shfl_xor(v, 2);  v += __shfl_xor(v, 4);
  v += __shfl_xor(v, 8);  v += __shfl_xor(v, 16); v += __shfl_xor(v, 32);
  __shared__ int wsum[4];
  if ((threadIdx.x & 63) == 0) wsum[threadIdx.x >> 6] = v;
  __syncthreads();
  if (threadIdx.x == 0) bsum[blockIdx.x] = wsum[0] + wsum[1] + wsum[2] + wsum[3];
}

__global__ __launch_bounds__(256) void scanB_k(int* __restrict__ bsum, int nblk,
                                               int* __restrict__ row_ptr, int n, int m) {
  const int i = threadIdx.x;
  const int lane = i & 63;
  const int wave = i >> 6;
  const int v = (i < nblk) ? bsum[i] : 0;
  int inc = v;
#pragma unroll
  for (int d = 1; d < 64; d <<= 1) {
    int t = __shfl_up(inc, d);
    if (lane >= d) inc += t;
  }
  __shared__ int wsum[4];
  if (lane == 63) wsum[wave] = inc;
  __syncthreads();
  int base = 0;
  for (int q = 0; q < wave; ++q) base += wsum[q];
  if (i < nblk) bsum[i] = base + inc - v;
  if (i == 0) row_ptr[n] = m;
}

__global__ __launch_bounds__(256) void scanC_k(const int* __restrict__ counts,
                                               const int* __restrict__ bsum,
                                               int* __restrict__ row_ptr,
                                               int* __restrict__ cursor, int n) {
  const int i = blockIdx.x * 256 + threadIdx.x;
  const int lane = threadIdx.x & 63;
  const int wave = threadIdx.x >> 6;
  const int v = (i < n) ? counts[i] : 0;
  int inc = v;
#pragma unroll
  for (int d = 1; d < 64; d <<= 1) {
    int t = __shfl_up(inc, d);
    if (lane >= d) inc += t;
  }
  __shared__ int wsum[4];
  if (lane == 63) wsum[wave] = inc;
  __syncthreads();
  int base = bsum[blockIdx.x];
  for (int q = 0; q < wave; ++q) base += wsum[q];
  const int excl = base + inc - v;
  if (i < n) { row_ptr[i] = excl; cursor[i] = excl; }
}

// ---------------------------------------------------------------------------
// One FULL routing layer (3 iterations fused), wave-per-node, 16 lanes/edge.
// REGISTER-RESIDENT edge cache (r13/r14 version, best measured -- FROZEN):
// first 16 edges gathered once (batched 2-latency chain), kept in zA..zD
// across all 3 iterations; deg>16 overflow re-gathered. Softmax denominator
// all-VALU DPP.
// MODE 1: dst = capsnorm(lrelu(u3))   (layer boundary)
// MODE 2: dst = lrelu(u3)             (final output)
// ---------------------------------------------------------------------------
template <int MODE>
__global__ __launch_bounds__(256) void rout_layer_k(
    const int* __restrict__ row_ptr, const int* __restrict__ src_sorted,
    const float* __restrict__ xn, float* __restrict__ dst, int n) {
  const int wid  = blockIdx.x * 4 + (threadIdx.x >> 6);
  const int lane = threadIdx.x & 63;
  if (wid >= n) return;
  const int g = lane >> 4;          // edge slot 0..3
  const int q = lane & 15;          // float4 chunk (dims 4q..4q+3)
  const size_t rowj = (size_t)wid * 64 + q * 4;
  const float4 fz = make_float4(0.f, 0.f, 0.f, 0.f);

  const float4 xj = *reinterpret_cast<const float4*>(xn + rowj);
  float u0 = xj.x, u1 = xj.y, u2 = xj.z, u3 = xj.w;   // u = x initially

  const int e0  = row_ptr[wid];
  const int end = row_ptr[wid + 1];
  const int ntile = (end - e0 + 3) >> 2;

  // ---- batched register gather of the first 16 edges ----
  const int eA = e0 + g, eB = eA + 4, eC = eA + 8, eD = eA + 12;
  const bool vA = eA < end, vB = eB < end, vC = eC < end, vD = eD < end;
  const int iA = vA ? src_sorted[eA] : wid;   // 4 independent index loads
  const int iB = vB ? src_sorted[eB] : wid;
  const int iC = vC ? src_sorted[eC] : wid;
  const int iD = vD ? src_sorted[eD] : wid;
  float4 zA = *reinterpret_cast<const float4*>(xn + (size_t)iA * 64 + q * 4);
  float4 zB = *reinterpret_cast<const float4*>(xn + (size_t)iB * 64 + q * 4);
  float4 zC = *reinterpret_cast<const float4*>(xn + (size_t)iC * 64 + q * 4);
  float4 zD = *reinterpret_cast<const float4*>(xn + (size_t)iD * 64 + q * 4);
  if (!vA) zA = fz;
  if (!vB) zB = fz;
  if (!vC) zC = fz;
  if (!vD) zD = fz;

  for (int t = 0; t < 3; ++t) {
    float a0 = 0.f, a1 = 0.f, a2 = 0.f, a3 = 0.f;

#define EDGE_BODY(Z)                                                   \
    {                                                                  \
      float d = (Z).x * u0;                                            \
      d = fmaf((Z).y, u1, d);                                          \
      d = fmaf((Z).z, u2, d);                                          \
      d = fmaf((Z).w, u3, d);                                          \
      d = dpp_add<0xB1>(d);              /* 8-dim capsule dot */       \
      const float ee = __expf(d);        /* |d|<=1: unit capsules */   \
      float sm = dpp_add<0x4E>(ee);      /* + capsule c^1        */    \
      sm = dpp_add<0x124>(sm);           /* + ror4               */    \
      sm = dpp_add<0x128>(sm);           /* + ror8: all 8 caps   */    \
      const float wgt = ee * __builtin_amdgcn_rcpf(sm);                \
      a0 = fmaf((Z).x, wgt, a0);                                       \
      a1 = fmaf((Z).y, wgt, a1);                                       \
      a2 = fmaf((Z).z, wgt, a2);                                       \
      a3 = fmaf((Z).w, wgt, a3);                                       \
    }

    EDGE_BODY(zA)
    EDGE_BODY(zB)
    EDGE_BODY(zC)
    EDGE_BODY(zD)
    for (int it = 4; it < ntile; ++it) {
      const int e = e0 + it * 4 + g;
      const bool vv = e < end;
      const int ss = vv ? src_sorted[e] : wid;
      float4 z = *reinterpret_cast<const float4*>(xn + (size_t)ss * 64 + q * 4);
      if (!vv) z = fz;
      EDGE_BODY(z)
    }
#undef EDGE_BODY

    // combine the 4 edge slots (lane bits 4,5)
    a0 += __shfl_xor(a0, 16); a0 += __shfl_xor(a0, 32);
    a1 += __shfl_xor(a1, 16); a1 += __shfl_xor(a1, 32);
    a2 += __shfl_xor(a2, 16); a2 += __shfl_xor(a2, 32);
    a3 += __shfl_xor(a3, 16); a3 += __shfl_xor(a3, 32);
    // + x, capsnorm -> next u
    a0 += xj.x; a1 += xj.y; a2 += xj.z; a3 += xj.w;
    float ss = a0 * a0 + a1 * a1 + a2 * a2 + a3 * a3;
    ss = dpp_add<0xB1>(ss);
    const float inv = 1.0f / fmaxf(sqrtf(ss), EPSN);
    u0 = a0 * inv; u1 = a1 * inv; u2 = a2 * inv; u3 = a3 * inv;
  }

  // boundary transforms
  float v0 = u0, v1 = u1, v2 = u2, v3 = u3;
  v0 = v0 > 0.f ? v0 : SLOPE * v0;
  v1 = v1 > 0.f ? v1 : SLOPE * v1;
  v2 = v2 > 0.f ? v2 : SLOPE * v2;
  v3 = v3 > 0.f ? v3 : SLOPE * v3;
  if (MODE == 1) {   // re-capsnorm for next layer's x
    float s3 = v0 * v0 + v1 * v1 + v2 * v2 + v3 * v3;
    s3 = dpp_add<0xB1>(s3);
    const float inv3 = 1.0f / fmaxf(sqrtf(s3), EPSN);
    v0 *= inv3; v1 *= inv3; v2 *= inv3; v3 *= inv3;
  }
  if (g == 0) {
    *reinterpret_cast<float4*>(dst + rowj) = make_float4(v0, v1, v2, v3);
  }
}

// ---------------------------------------------------------------------------
extern "C" void kernel_launch(void* const* d_in, const int* in_sizes, int n_in,
                              void* d_out, int out_size, void* d_ws, size_t ws_size,
                              hipStream_t stream) {
  const float* x       = (const float*)d_in[0];
  const int*   src_trg = (const int*)d_in[1];
  const float* W       = (const float*)d_in[2];
  const float* b       = (const float*)d_in[3];

  const int hid    = in_sizes[3];          // 64
  const int in_dim = in_sizes[2] / hid;    // 500
  const int n      = in_sizes[0] / in_dim; // 50000
  const int m      = in_sizes[1] / 2;      // 500000
  const int* src = src_trg;
  const int* trg = src_trg + m;

  const size_t n64 = (size_t)n * hid;      // 3.2M floats
  float* xn_a = (float*)d_ws;              // layer-1 normalized features
  float* xn_b = xn_a + n64;                // layer-2 normalized features
  short* w2h  = (short*)(xn_b + n64);      // KPAD*64 bf16 hi (swizzled)
  short* w2l  = w2h + KPAD * 64;           // KPAD*64 bf16 lo
  float* zbuf = (float*)(w2l + KPAD * 64); // 16B zero granule (A-tail redirect)
  int*   ip   = (int*)(zbuf + 4);
  int* counts     = ip;                    // n
  int* row_ptr    = counts + n;            // n+1
  int* cursor     = row_ptr + n + 1;       // n
  int* bsum       = cursor + n;            // nblk
  const int nblk  = (n + 255) / 256;       // 196 (<= 256 required by scanB)
  int* src_sorted = bsum + nblk;           // m
  float* out = (float*)d_out;

  const int mg = (m + 255) / 256;          // 1954 edge blocks
  const int gemm_blocks = (n + 63) / 64;   // 782

  // --- phase 1: memset counts, then fused {prep_w ∥ hist} ---
  hipMemsetAsync(counts, 0, (size_t)n * sizeof(int), stream);
  prep_hist_k<<<PREP_BLOCKS + mg, 256, 0, stream>>>(
      W, w2h, w2l, zbuf, in_dim, trg, counts, m);

  // --- phase 2: scan chain (row_ptr, cursor) ---
  scanA_k<<<nblk, 256, 0, stream>>>(counts, bsum, n);
  scanB_k<<<1, 256, 0, stream>>>(bsum, nblk, row_ptr, n, m);
  scanC_k<<<nblk, 256, 0, stream>>>(counts, bsum, row_ptr, cursor, n);

  // --- phase 3: fused {GEMM ∥ scatter} (disjoint outputs; scatter fills
  //     the latency-bound GEMM's idle issue slots) ---
  gemm_scatter_k<<<gemm_blocks + mg, 256, 0, stream>>>(
      x, w2h, w2l, b, zbuf, xn_a, n, in_dim,
      src, trg, cursor, src_sorted, m, gemm_blocks);

  // --- phase 4: routing, one fused kernel per layer ---
  const int rb = (n + 3) / 4;  // 4 waves (nodes) per 256-thread block
  rout_layer_k<1><<<rb, 256, 0, stream>>>(row_ptr, src_sorted, xn_a, xn_b, n);
  rout_layer_k<2><<<rb, 256, 0, stream>>>(row_ptr, src_sorted, xn_b, out, n);
}